// Round 15
// baseline (693.264 us; speedup 1.0000x reference)
//
#include <hip/hip_runtime.h>
#include <stdint.h>

// ---------------- problem constants ----------------
#define NCODES 8192
#define DIM 256
#define NROWS 65536  // 16*64*64

// d_out layout (f32 elements): z_q | codebook_loss | commitment_loss | indices
#define OUT_L0 16777216
#define OUT_L1 16777217
#define OUT_IDX 16777218

// workspace byte offsets
#define WS_IMG 0u         // u16[8192*256] f16 hi image of w*8192
#define WS_IMGL 4194304u  // u16[8192*256] f16 lo image (residual)
#define WS_HV 8388608u    // float[8192]   fl32(4096*||e||^2)
#define WS_C32 8421376u   // float[8192]   np-replica f32 ||e||^2
#define WS_A32 8454144u   // float[65536]  np-replica f32 ||z||^2
#define WS_TOP3 8716288u  // int4[65536]   (i1,i2,i3, v1<<1|flag)
#define WS_DROW 9764864u  // double[65536] per-row exact d^2 of winner
#define WS_CNT 10289152u  // int[2]: flagged count, candidate count
#define WS_LIST 10289168u // int[65536] flagged rows
#define WS_MKEY 10551312u // u64[65536] atomicMin keys (flagged)
#define WS_VMIN 11075600u // u32[65536] rescreen per-row min (mono f32)
#define WS_CAND 11337744u // int2[262144] (row, code) candidates
#define MAXC 262144

// flag threshold: 0.40 v-units * 512 int-units/v = 204.8 -> 205
#define TAU_INT 205u
// rescreen collect margin: np-grid 0.25 + 2x rescreen err ~0.004 -> 0.30
#define MARG 0.30f

typedef __attribute__((ext_vector_type(8))) short s8v;
typedef __attribute__((ext_vector_type(8))) _Float16 f16x8;
typedef __attribute__((ext_vector_type(4))) float f4v;
typedef unsigned short u16;
typedef unsigned long long u64;

__device__ __forceinline__ u16 f2h_bits(float x) {
  return __builtin_bit_cast(u16, (_Float16)x);
}
// monotone f32 -> u32 order map
__device__ __forceinline__ unsigned fmono(float v) {
  unsigned u = __float_as_uint(v);
  return u ^ ((unsigned)((int)u >> 31) | 0x80000000u);
}
__device__ __forceinline__ float fmono_inv(unsigned m) {
  unsigned u = m ^ (~((unsigned)((int)m >> 31)) | 0x80000000u);
  return __uint_as_float(u);
}
// np f32 score: s = fl(fl(A - fl(2*Gf)) + C)  (exact IEEE f32 op sequence)
__device__ __forceinline__ float np_score(float A, float Gf, float C) {
  const float g2 = 2.0f * Gf;
  const float t = A - g2;
  return t + C;
}
// single-instruction median-of-3 (gfx9+): sorted-quad insert primitive
__device__ __forceinline__ unsigned med3u(unsigned a, unsigned b, unsigned c) {
  unsigned d;
  asm("v_med3_u32 %0, %1, %2, %3" : "=v"(d) : "v"(a), "v"(b), "v"(c));
  return d;
}

// ---------------- rowA: np-pairwise-replica f32 sum of x_d^2 per row ----------------
__global__ __launch_bounds__(256) void vq_rowA(const float* __restrict__ x,
                                               float* __restrict__ out) {
  __shared__ float sq[4][256];
  __shared__ float rb[4][16];
  const int wv = threadIdx.x >> 6, lane = threadIdx.x & 63;
  const int row = blockIdx.x * 4 + wv;
  const float4 v = *(const float4*)(x + (size_t)row * DIM + lane * 4);
  sq[wv][lane * 4 + 0] = v.x * v.x;
  sq[wv][lane * 4 + 1] = v.y * v.y;
  sq[wv][lane * 4 + 2] = v.z * v.z;
  sq[wv][lane * 4 + 3] = v.w * v.w;
  __syncthreads();
  if (lane < 16) {
    const int j = lane & 7, hb = (lane >> 3) * 128;
    float r = sq[wv][hb + j];
    for (int i = 1; i < 16; ++i) r += sq[wv][hb + i * 8 + j];  // sequential, ascending
    rb[wv][lane] = r;
  }
  __syncthreads();
  if (lane == 0) {
    const float* r = rb[wv];
    const float h0 = ((r[0] + r[1]) + (r[2] + r[3])) + ((r[4] + r[5]) + (r[6] + r[7]));
    const float h1 = ((r[8] + r[9]) + (r[10] + r[11])) + ((r[12] + r[13]) + (r[14] + r[15]));
    out[row] = h0 + h1;
  }
}

// ---------------- prep: f16 hi+lo images (x8192) + hv + zero counters ----------------
__global__ __launch_bounds__(256) void vq_prep(const float* __restrict__ w,
                                               u16* __restrict__ imgh,
                                               u16* __restrict__ imgl,
                                               float* __restrict__ hv,
                                               int* __restrict__ cnt) {
  if (blockIdx.x == 0 && threadIdx.x == 0) { cnt[0] = 0; cnt[1] = 0; }
  const int wv = threadIdx.x >> 6, lane = threadIdx.x & 63;
  const int code = blockIdx.x * 4 + wv;
  const float4 v = *(const float4*)(w + (size_t)code * DIM + lane * 4);
  float xs[4] = {v.x * 8192.0f, v.y * 8192.0f, v.z * 8192.0f, v.w * 8192.0f};
  ushort4 uh, ul;
  unsigned short* ph = (unsigned short*)&uh;
  unsigned short* pl = (unsigned short*)&ul;
#pragma unroll
  for (int k = 0; k < 4; ++k) {
    const _Float16 h = (_Float16)xs[k];
    ph[k] = __builtin_bit_cast(u16, h);
    pl[k] = __builtin_bit_cast(u16, (_Float16)(xs[k] - (float)h));
  }
  *(ushort4*)(imgh + (size_t)code * DIM + lane * 4) = uh;
  *(ushort4*)(imgl + (size_t)code * DIM + lane * 4) = ul;
  double s = 0.0;
  s = fma((double)v.x, (double)v.x, s);
  s = fma((double)v.y, (double)v.y, s);
  s = fma((double)v.z, (double)v.z, s);
  s = fma((double)v.w, (double)v.w, s);
#pragma unroll
  for (int m = 1; m <= 32; m <<= 1) s += __shfl_xor(s, m, 64);
  if (lane == 0) hv[code] = (float)(4096.0 * s);
}

// merge two ascending sorted 4-tuples -> smallest 4 of union
#define MERGE4(a1, a2, a3, a4, b1, b2, b3, b4)                          \
  {                                                                     \
    const unsigned x11 = max(a1, b1);                                   \
    const unsigned o1 = min(a1, b1);                                    \
    const unsigned o2 = min(min(a2, b2), x11);                          \
    const unsigned x21 = max(a2, b1), x12 = max(a1, b2);                \
    const unsigned o3 = min(min(a3, b3), min(x21, x12));                \
    const unsigned x31 = max(a3, b1), x22 = max(a2, b2), x13 = max(a1, b3); \
    const unsigned o4 = min(min(a4, b4), min(min(x31, x22), x13));      \
    a1 = o1; a2 = o2; a3 = o3; a4 = o4;                                 \
  }

// ---------------- main: LDS-staged f16 MFMA + per-row top-4 int keys + flag ----------------
// r12-verbatim structure (333us). grid 512 x 256; wave owns 32 rows, all 8192 codes.
__global__ __launch_bounds__(256, 3) void vq_main(const float* __restrict__ z,
                                                  const u16* __restrict__ img,
                                                  const float* __restrict__ hv,
                                                  int4* __restrict__ top3,
                                                  int* __restrict__ cnt,
                                                  int* __restrict__ list,
                                                  u64* __restrict__ mkey,
                                                  unsigned* __restrict__ vminG) {
  __shared__ __align__(16) char lds[2][16384];
  const int tid = threadIdx.x, wv = tid >> 6, lane = tid & 63;
  const int ll = lane & 15, lh = lane >> 4;
  const int myrow = blockIdx.x * 128 + wv * 32;

  f16x8 A[2][8];
#pragma unroll
  for (int rt = 0; rt < 2; ++rt) {
    const float* zr = z + (size_t)(myrow + rt * 16 + ll) * DIM;
#pragma unroll
    for (int c = 0; c < 8; ++c) {
      const float4 a = *(const float4*)(zr + c * 32 + lh * 8);
      const float4 b = *(const float4*)(zr + c * 32 + lh * 8 + 4);
      f16x8 t;
      t[0] = (_Float16)a.x; t[1] = (_Float16)a.y;
      t[2] = (_Float16)a.z; t[3] = (_Float16)a.w;
      t[4] = (_Float16)b.x; t[5] = (_Float16)b.y;
      t[6] = (_Float16)b.z; t[7] = (_Float16)b.w;
      A[rt][c] = t;
    }
  }

  unsigned k1[8], k2[8], k3[8], k4[8];
#pragma unroll
  for (int s = 0; s < 8; ++s) {
    k1[s] = 0xFFFFFFFFu; k2[s] = 0xFFFFFFFFu;
    k3[s] = 0xFFFFFFFFu; k4[s] = 0xFFFFFFFFu;
  }

  unsigned soff[4];
#pragma unroll
  for (int p = 0; p < 4; ++p)
    soff[p] = (unsigned)((lane & 31) * 512 + ((p * 4 + wv) * 2 + (lane >> 5)) * 16);

  auto STAGE = [&](int t, int buf) {
    const char* src = (const char*)img + (size_t)t * 16384;
#pragma unroll
    for (int p = 0; p < 4; ++p) {
      __builtin_amdgcn_global_load_lds(
          (const __attribute__((address_space(1))) unsigned int*)(src + soff[p]),
          (__attribute__((address_space(3))) unsigned int*)(&lds[buf][(p * 4 + wv) * 1024]),
          16, 0, 0);
    }
  };

  const int rbase = lh * 512 + ll * 16;

  STAGE(0, 0);
  __syncthreads();
#pragma unroll 1
  for (int t = 0; t < 256; ++t) {
    const int buf = t & 1;
    if (t + 1 < 256) STAGE(t + 1, buf ^ 1);

    const float hb0 = fmaf(hv[t * 32 + ll], 512.0f, 262144.0f);  // (hv+512)*512
    const float hb1 = fmaf(hv[t * 32 + 16 + ll], 512.0f, 262144.0f);
    const char* bp = &lds[buf][rbase];

    f4v a00 = (f4v){0.f, 0.f, 0.f, 0.f}, a01 = (f4v){0.f, 0.f, 0.f, 0.f};
    f4v a10 = (f4v){0.f, 0.f, 0.f, 0.f}, a11 = (f4v){0.f, 0.f, 0.f, 0.f};
#pragma unroll
    for (int c = 0; c < 8; ++c) {
      const f16x8 b0 = *(const f16x8*)(bp + c * 2048);
      const f16x8 b1 = *(const f16x8*)(bp + c * 2048 + 256);
      a00 = __builtin_amdgcn_mfma_f32_16x16x32_f16(A[0][c], b0, a00, 0, 0, 0);
      a01 = __builtin_amdgcn_mfma_f32_16x16x32_f16(A[0][c], b1, a01, 0, 0, 0);
      a10 = __builtin_amdgcn_mfma_f32_16x16x32_f16(A[1][c], b0, a10, 0, 0, 0);
      a11 = __builtin_amdgcn_mfma_f32_16x16x32_f16(A[1][c], b1, a11, 0, 0, 0);
    }

    const unsigned iv0 = (unsigned)(t * 32 + ll);
    const unsigned iv1 = iv0 + 16u;
#pragma unroll
    for (int rt = 0; rt < 2; ++rt) {
      const f4v& c0 = rt ? a10 : a00;
      const f4v& c1 = rt ? a11 : a01;
#pragma unroll
      for (int j = 0; j < 4; ++j) {
        const int s = rt * 4 + j;
        const float u0 = fmaf(c0[j], -512.0f, hb0);
        const unsigned key0 = (((unsigned)u0) << 13) | iv0;
        const unsigned n1 = min(k1[s], key0);
        const unsigned n2 = med3u(k1[s], key0, k2[s]);
        const unsigned n3 = med3u(k2[s], key0, k3[s]);
        const unsigned n4 = med3u(k3[s], key0, k4[s]);
        const float u1 = fmaf(c1[j], -512.0f, hb1);
        const unsigned key1 = (((unsigned)u1) << 13) | iv1;
        k1[s] = min(n1, key1);
        k2[s] = med3u(n1, key1, n2);
        k3[s] = med3u(n2, key1, n3);
        k4[s] = med3u(n3, key1, n4);
      }
    }
    __syncthreads();
  }

#pragma unroll
  for (int rt = 0; rt < 2; ++rt)
#pragma unroll
    for (int j = 0; j < 4; ++j) {
      const int s = rt * 4 + j;
      unsigned a1 = k1[s], a2 = k2[s], a3 = k3[s], a4 = k4[s];
#pragma unroll
      for (int m = 1; m <= 8; m <<= 1) {
        unsigned b1 = (unsigned)__shfl_xor((int)a1, m, 64);
        unsigned b2 = (unsigned)__shfl_xor((int)a2, m, 64);
        unsigned b3 = (unsigned)__shfl_xor((int)a3, m, 64);
        unsigned b4 = (unsigned)__shfl_xor((int)a4, m, 64);
        MERGE4(a1, a2, a3, a4, b1, b2, b3, b4);
      }
      if (ll == 0) {  // C/D: col=lane&15, row=(lane>>4)*4+j
        const int row = myrow + rt * 16 + lh * 4 + j;
        const int flag = ((a4 >> 13) - (a1 >> 13)) < TAU_INT ? 1 : 0;
        top3[row] = make_int4((int)(a1 & 0x1FFFu), (int)(a2 & 0x1FFFu), (int)(a3 & 0x1FFFu),
                              (int)(((a1 >> 13) << 1) | (unsigned)flag));
        if (flag) {
          mkey[row] = ~0ull;
          vminG[row] = 0xFFFFFFFFu;
          list[atomicAdd(cnt, 1)] = row;
        }
      }
    }
}

// ---------------- refine (unflagged): np-replica s over top-3, first-index tie ----------------
__global__ __launch_bounds__(256) void vq_refine(const float* __restrict__ z,
                                                 const float* __restrict__ w,
                                                 const float* __restrict__ A32,
                                                 const float* __restrict__ C32,
                                                 const int4* __restrict__ top3,
                                                 float* __restrict__ out,
                                                 double* __restrict__ drow) {
  const int wv = threadIdx.x >> 6, lane = threadIdx.x & 63;
  const int row = blockIdx.x * 4 + wv;
  const int4 cc = top3[row];
  if (cc.w & 1) return;  // flagged -> rescreen path owns this row
  const float4 zv = *(const float4*)(z + (size_t)row * DIM + lane * 4);
  const double z0 = (double)zv.x, z1 = (double)zv.y, z2 = (double)zv.z, z3 = (double)zv.w;
  const int cand[3] = {cc.x, cc.y, cc.z};
  float4 ev[3];
  float sc[3];
  const float A = A32[row];
#pragma unroll
  for (int k = 0; k < 3; ++k) {
    ev[k] = *(const float4*)(w + (size_t)cand[k] * DIM + lane * 4);
    double d = 0.0;
    d = fma(z0, (double)ev[k].x, d);
    d = fma(z1, (double)ev[k].y, d);
    d = fma(z2, (double)ev[k].z, d);
    d = fma(z3, (double)ev[k].w, d);
#pragma unroll
    for (int m = 1; m <= 32; m <<= 1) d += __shfl_xor(d, m, 64);
    sc[k] = np_score(A, (float)d, C32[cand[k]]);
  }
  int win = cand[0], wk = 0;
  float sw = sc[0];
#pragma unroll
  for (int k = 1; k < 3; ++k) {
    const bool take = (sc[k] < sw) || (sc[k] == sw && cand[k] < win);
    sw = take ? sc[k] : sw;
    win = take ? cand[k] : win;
    wk = take ? k : wk;
  }
  const float4 q = ev[wk];
  *(float4*)(out + (size_t)row * DIM + lane * 4) = q;
  double dd = 0.0, tt;
  tt = (double)zv.x - (double)q.x; dd = fma(tt, tt, dd);
  tt = (double)zv.y - (double)q.y; dd = fma(tt, tt, dd);
  tt = (double)zv.z - (double)q.z; dd = fma(tt, tt, dd);
  tt = (double)zv.w - (double)q.w; dd = fma(tt, tt, dd);
#pragma unroll
  for (int m = 1; m <= 32; m <<= 1) dd += __shfl_xor(dd, m, 64);
  if (lane == 0) {
    out[OUT_IDX + row] = (float)win;
    drow[row] = dd;
  }
}

// ---------------- rescreen (flagged rows): 3-pass split-f16 MFMA ----------------
// PASS 0: per-row min of v (err ~2e-3 v-units) -> vminG (mono-u32 atomicMin).
// PASS 1: emit all codes with v <= vmin + MARG into cands (provably contains
// the np-winner and all its tie-competitors). Block = 128 gathered rows x
// one tile-quarter (64 tiles); grid 256 = 64 chunk-slots x 4 quarters.
template <int PASS>
__global__ __launch_bounds__(256, 2) void vq_rescreen(const float* __restrict__ z,
                                                      const u16* __restrict__ imgh,
                                                      const u16* __restrict__ imgl,
                                                      const float* __restrict__ hv,
                                                      const int* __restrict__ cnt,
                                                      const int* __restrict__ list,
                                                      unsigned* __restrict__ vminG,
                                                      int* __restrict__ gcnt,
                                                      int2* __restrict__ cands) {
  __shared__ __align__(16) char lds[2][32768];  // hi 16K | lo 16K per buffer
  const int tid = threadIdx.x, wv = tid >> 6, lane = tid & 63;
  const int ll = lane & 15, lh = lane >> 4;
  const int n = *cnt;
  const int q = blockIdx.x & 3;
  unsigned soff[4];
#pragma unroll
  for (int p = 0; p < 4; ++p)
    soff[p] = (unsigned)((lane & 31) * 512 + ((p * 4 + wv) * 2 + (lane >> 5)) * 16);
  const int rbase = lh * 512 + ll * 16;

#pragma unroll 1
  for (int chunk = (int)(blockIdx.x >> 2); chunk * 128 < n; chunk += 64) {
    // A fragments hi/lo for this wave's 32 gathered rows
    f16x8 Ah[2][8], Al[2][8];
#pragma unroll
    for (int rt = 0; rt < 2; ++rt) {
      const int ri = min(chunk * 128 + wv * 32 + rt * 16 + ll, n - 1);
      const float* zr = z + (size_t)list[ri] * DIM;
#pragma unroll
      for (int c = 0; c < 8; ++c) {
        const float4 a = *(const float4*)(zr + c * 32 + lh * 8);
        const float4 b = *(const float4*)(zr + c * 32 + lh * 8 + 4);
        float xs[8] = {a.x, a.y, a.z, a.w, b.x, b.y, b.z, b.w};
        f16x8 th, tl;
#pragma unroll
        for (int k = 0; k < 8; ++k) {
          const _Float16 h = (_Float16)xs[k];
          th[k] = h;
          tl[k] = (_Float16)(xs[k] - (float)h);
        }
        Ah[rt][c] = th;
        Al[rt][c] = tl;
      }
    }
    // per-slot state: output-row index, running min / collect limit
    float vmin[2][4], vlim[2][4];
    int rowv[2][4];
#pragma unroll
    for (int rt = 0; rt < 2; ++rt)
#pragma unroll
      for (int j = 0; j < 4; ++j) {
        const int ri = min(chunk * 128 + wv * 32 + rt * 16 + lh * 4 + j, n - 1);
        rowv[rt][j] = list[ri];
        vmin[rt][j] = 3.0e38f;
        if (PASS == 1) vlim[rt][j] = fmono_inv(vminG[rowv[rt][j]]) + MARG;
      }

    auto STAGE = [&](int t, int buf) {
      const char* sh = (const char*)imgh + (size_t)t * 16384;
      const char* sl = (const char*)imgl + (size_t)t * 16384;
#pragma unroll
      for (int p = 0; p < 4; ++p) {
        __builtin_amdgcn_global_load_lds(
            (const __attribute__((address_space(1))) unsigned int*)(sh + soff[p]),
            (__attribute__((address_space(3))) unsigned int*)(&lds[buf][(p * 4 + wv) * 1024]),
            16, 0, 0);
        __builtin_amdgcn_global_load_lds(
            (const __attribute__((address_space(1))) unsigned int*)(sl + soff[p]),
            (__attribute__((address_space(3))) unsigned int*)(&lds[buf][16384 + (p * 4 + wv) * 1024]),
            16, 0, 0);
      }
    };

    STAGE(q * 64, 0);
    __syncthreads();
#pragma unroll 1
    for (int tt = 0; tt < 64; ++tt) {
      const int t = q * 64 + tt, buf = tt & 1;
      if (tt + 1 < 64) STAGE(q * 64 + tt + 1, buf ^ 1);
      const float hv0 = hv[t * 32 + ll], hv1 = hv[t * 32 + 16 + ll];
      const char* bp = &lds[buf][rbase];

      f4v a00 = (f4v){0.f, 0.f, 0.f, 0.f}, a01 = (f4v){0.f, 0.f, 0.f, 0.f};
      f4v a10 = (f4v){0.f, 0.f, 0.f, 0.f}, a11 = (f4v){0.f, 0.f, 0.f, 0.f};
#pragma unroll
      for (int c = 0; c < 8; ++c) {
        const f16x8 bh0 = *(const f16x8*)(bp + c * 2048);
        const f16x8 bh1 = *(const f16x8*)(bp + c * 2048 + 256);
        const f16x8 bl0 = *(const f16x8*)(bp + 16384 + c * 2048);
        const f16x8 bl1 = *(const f16x8*)(bp + 16384 + c * 2048 + 256);
        a00 = __builtin_amdgcn_mfma_f32_16x16x32_f16(Ah[0][c], bh0, a00, 0, 0, 0);
        a00 = __builtin_amdgcn_mfma_f32_16x16x32_f16(Al[0][c], bh0, a00, 0, 0, 0);
        a00 = __builtin_amdgcn_mfma_f32_16x16x32_f16(Ah[0][c], bl0, a00, 0, 0, 0);
        a01 = __builtin_amdgcn_mfma_f32_16x16x32_f16(Ah[0][c], bh1, a01, 0, 0, 0);
        a01 = __builtin_amdgcn_mfma_f32_16x16x32_f16(Al[0][c], bh1, a01, 0, 0, 0);
        a01 = __builtin_amdgcn_mfma_f32_16x16x32_f16(Ah[0][c], bl1, a01, 0, 0, 0);
        a10 = __builtin_amdgcn_mfma_f32_16x16x32_f16(Ah[1][c], bh0, a10, 0, 0, 0);
        a10 = __builtin_amdgcn_mfma_f32_16x16x32_f16(Al[1][c], bh0, a10, 0, 0, 0);
        a10 = __builtin_amdgcn_mfma_f32_16x16x32_f16(Ah[1][c], bl0, a10, 0, 0, 0);
        a11 = __builtin_amdgcn_mfma_f32_16x16x32_f16(Ah[1][c], bh1, a11, 0, 0, 0);
        a11 = __builtin_amdgcn_mfma_f32_16x16x32_f16(Al[1][c], bh1, a11, 0, 0, 0);
        a11 = __builtin_amdgcn_mfma_f32_16x16x32_f16(Ah[1][c], bl1, a11, 0, 0, 0);
      }

#pragma unroll
      for (int rt = 0; rt < 2; ++rt) {
        const f4v& c0 = rt ? a10 : a00;
        const f4v& c1 = rt ? a11 : a01;
#pragma unroll
        for (int j = 0; j < 4; ++j) {
          const float v0 = hv0 - c0[j];
          const float v1 = hv1 - c1[j];
          if (PASS == 0) {
            vmin[rt][j] = fminf(vmin[rt][j], fminf(v0, v1));
          } else {
            if (v0 <= vlim[rt][j]) {
              const int slot = atomicAdd(gcnt, 1);
              if (slot < MAXC) cands[slot] = make_int2(rowv[rt][j], t * 32 + ll);
            }
            if (v1 <= vlim[rt][j]) {
              const int slot = atomicAdd(gcnt, 1);
              if (slot < MAXC) cands[slot] = make_int2(rowv[rt][j], t * 32 + 16 + ll);
            }
          }
        }
      }
      __syncthreads();
    }

    if (PASS == 0) {
#pragma unroll
      for (int rt = 0; rt < 2; ++rt)
#pragma unroll
        for (int j = 0; j < 4; ++j) {
          float vm = vmin[rt][j];
#pragma unroll
          for (int m = 1; m <= 8; m <<= 1) vm = fminf(vm, __shfl_xor(vm, m, 64));
          if (ll == 0) atomicMin(&vminG[rowv[rt][j]], fmono(vm));
        }
    }
    __syncthreads();
  }
}

// ---------------- exact: np-replica score per candidate -> atomicMin key ----------------
__global__ __launch_bounds__(256) void vq_exact(const float* __restrict__ z,
                                                const float* __restrict__ w,
                                                const float* __restrict__ A32,
                                                const float* __restrict__ C32,
                                                const int* __restrict__ gcnt,
                                                const int2* __restrict__ cands,
                                                u64* __restrict__ mkey) {
  const int wv = threadIdx.x >> 6, lane = threadIdx.x & 63;
  const int m = min(*gcnt, MAXC);
  for (int k = blockIdx.x * 4 + wv; k < m; k += 1024) {
    const int2 c = cands[k];
    const float4 zv = *(const float4*)(z + (size_t)c.x * DIM + lane * 4);
    const float4 ev = *(const float4*)(w + (size_t)c.y * DIM + lane * 4);
    double d = 0.0;
    d = fma((double)zv.x, (double)ev.x, d);
    d = fma((double)zv.y, (double)ev.y, d);
    d = fma((double)zv.z, (double)ev.z, d);
    d = fma((double)zv.w, (double)ev.w, d);
#pragma unroll
    for (int mm = 1; mm <= 32; mm <<= 1) d += __shfl_xor(d, mm, 64);
    const float s = np_score(A32[c.x], (float)d, C32[c.y]);
    if (lane == 0) atomicMin(&mkey[c.x], ((u64)fmono(s) << 13) | (u64)c.y);
  }
}

// ---------------- fallback write: winner -> z_q, idx, drow ----------------
__global__ __launch_bounds__(256) void vq_fb_write(const float* __restrict__ z,
                                                   const float* __restrict__ w,
                                                   const int* __restrict__ cnt,
                                                   const int* __restrict__ list,
                                                   const u64* __restrict__ mkey,
                                                   float* __restrict__ out,
                                                   double* __restrict__ drow) {
  const int wv = threadIdx.x >> 6, lane = threadIdx.x & 63;
  const int n = *cnt;
  for (int k = blockIdx.x * 4 + wv; k < n; k += 1024) {
    const int row = list[k];
    const int win = (int)(mkey[row] & 0x1FFFull);
    const float4 zv = *(const float4*)(z + (size_t)row * DIM + lane * 4);
    const float4 q = *(const float4*)(w + (size_t)win * DIM + lane * 4);
    *(float4*)(out + (size_t)row * DIM + lane * 4) = q;
    double dd = 0.0, tt;
    tt = (double)zv.x - (double)q.x; dd = fma(tt, tt, dd);
    tt = (double)zv.y - (double)q.y; dd = fma(tt, tt, dd);
    tt = (double)zv.z - (double)q.z; dd = fma(tt, tt, dd);
    tt = (double)zv.w - (double)q.w; dd = fma(tt, tt, dd);
#pragma unroll
    for (int m = 1; m <= 32; m <<= 1) dd += __shfl_xor(dd, m, 64);
    if (lane == 0) {
      out[OUT_IDX + row] = (float)win;
      drow[row] = dd;
    }
  }
}

// ---------------- loss: deterministic f64 reduction ----------------
__global__ __launch_bounds__(256) void vq_loss(const double* __restrict__ drow,
                                               float* __restrict__ out) {
  __shared__ double sd[256];
  double s = 0.0;
  for (int i = threadIdx.x; i < NROWS; i += 256) s += drow[i];
  sd[threadIdx.x] = s;
  __syncthreads();
  if (threadIdx.x == 0) {
    double tot = 0.0;
    for (int i = 0; i < 256; ++i) tot += sd[i];
    const float loss = (float)(tot / 16777216.0);
    out[OUT_L0] = loss;
    out[OUT_L1] = loss;
  }
}

extern "C" void kernel_launch(void* const* d_in, const int* in_sizes, int n_in,
                              void* d_out, int out_size, void* d_ws, size_t ws_size,
                              hipStream_t stream) {
  const float* z = (const float*)d_in[0];  // f32 [65536, 256]
  const float* w = (const float*)d_in[1];  // f32 [8192, 256]
  float* out = (float*)d_out;
  unsigned char* ws = (unsigned char*)d_ws;
  u16* imgh = (u16*)(ws + WS_IMG);
  u16* imgl = (u16*)(ws + WS_IMGL);
  float* hv = (float*)(ws + WS_HV);
  float* C32 = (float*)(ws + WS_C32);
  float* A32 = (float*)(ws + WS_A32);
  int4* top3 = (int4*)(ws + WS_TOP3);
  double* drow = (double*)(ws + WS_DROW);
  int* cnt = (int*)(ws + WS_CNT);       // [0]=flagged, [1]=cands
  int* list = (int*)(ws + WS_LIST);
  u64* mkey = (u64*)(ws + WS_MKEY);
  unsigned* vminG = (unsigned*)(ws + WS_VMIN);
  int2* cands = (int2*)(ws + WS_CAND);

  vq_prep<<<NCODES / 4, 256, 0, stream>>>(w, imgh, imgl, hv, cnt);
  vq_rowA<<<NCODES / 4, 256, 0, stream>>>(w, C32);
  vq_rowA<<<NROWS / 4, 256, 0, stream>>>(z, A32);
  vq_main<<<NROWS / 128, 256, 0, stream>>>(z, imgh, hv, top3, cnt, list, mkey, vminG);
  vq_refine<<<NROWS / 4, 256, 0, stream>>>(z, w, A32, C32, top3, out, drow);
  vq_rescreen<0><<<256, 256, 0, stream>>>(z, imgh, imgl, hv, cnt, list, vminG, cnt + 1, cands);
  vq_rescreen<1><<<256, 256, 0, stream>>>(z, imgh, imgl, hv, cnt, list, vminG, cnt + 1, cands);
  vq_exact<<<256, 256, 0, stream>>>(z, w, A32, C32, cnt + 1, cands, mkey);
  vq_fb_write<<<256, 256, 0, stream>>>(z, w, cnt, list, mkey, out, drow);
  vq_loss<<<1, 256, 0, stream>>>(drow, out);
}

// Round 16
// 540.898 us; speedup vs baseline: 1.2817x; 1.2817x over previous
//
#include <hip/hip_runtime.h>
#include <stdint.h>

// ---------------- problem constants ----------------
#define NCODES 8192
#define DIM 256
#define NROWS 65536  // 16*64*64

// d_out layout (f32 elements): z_q | codebook_loss | commitment_loss | indices
#define OUT_L0 16777216
#define OUT_L1 16777217
#define OUT_IDX 16777218

// workspace byte offsets
#define WS_IMG 0u         // u16[8192*256] f16 hi image of w*8192
#define WS_IMGL 4194304u  // u16[8192*256] f16 lo image (residual)
#define WS_HV 8388608u    // float[8192]   fl32(4096*||e||^2)
#define WS_C32 8421376u   // float[8192]   np-replica f32 ||e||^2
#define WS_A32 8454144u   // float[65536]  np-replica f32 ||z||^2
#define WS_TOP3 8716288u  // int4[65536]   (i1,i2,i3, v1<<1|flag)
#define WS_DROW 9764864u  // double[65536] per-row exact d^2 of winner
#define WS_CNT 10289152u  // int[2]: flagged count, candidate count
#define WS_LIST 10289168u // int[65536] flagged rows
#define WS_MKEY 10551312u // u64[65536] atomicMin keys (flagged)
#define WS_VMIN 11075600u // u32[65536] fb per-row accurate min (mono f32)
#define WS_CAND 11337744u // int2[262144] (row, code) candidates
#define MAXC 262144

// flag threshold: 0.40 v-units * 512 int-units/v = 204.8 -> 205
#define TAU_INT 205u
// fb collect margin: np worst-case 0.38 + 2x split-dot err 0.01 -> 0.45 (proven)
#define MARG 0.45f

typedef __attribute__((ext_vector_type(8))) short s8v;
typedef __attribute__((ext_vector_type(8))) _Float16 f16x8;
typedef __attribute__((ext_vector_type(4))) float f4v;
typedef unsigned short u16;
typedef unsigned long long u64;

__device__ __forceinline__ u16 f2h_bits(float x) {
  return __builtin_bit_cast(u16, (_Float16)x);
}
// monotone f32 -> u32 order map
__device__ __forceinline__ unsigned fmono(float v) {
  unsigned u = __float_as_uint(v);
  return u ^ ((unsigned)((int)u >> 31) | 0x80000000u);
}
__device__ __forceinline__ float fmono_inv(unsigned m) {
  unsigned u = m ^ (~((unsigned)((int)m >> 31)) | 0x80000000u);
  return __uint_as_float(u);
}
// np f32 score: s = fl(fl(A - fl(2*Gf)) + C)  (exact IEEE f32 op sequence)
__device__ __forceinline__ float np_score(float A, float Gf, float C) {
  const float g2 = 2.0f * Gf;
  const float t = A - g2;
  return t + C;
}
// single-instruction median-of-3 (gfx9+): sorted-quad insert primitive
__device__ __forceinline__ unsigned med3u(unsigned a, unsigned b, unsigned c) {
  unsigned d;
  asm("v_med3_u32 %0, %1, %2, %3" : "=v"(d) : "v"(a), "v"(b), "v"(c));
  return d;
}

// ---------------- rowA: np-pairwise-replica f32 sum of x_d^2 per row ----------------
__global__ __launch_bounds__(256) void vq_rowA(const float* __restrict__ x,
                                               float* __restrict__ out) {
  __shared__ float sq[4][256];
  __shared__ float rb[4][16];
  const int wv = threadIdx.x >> 6, lane = threadIdx.x & 63;
  const int row = blockIdx.x * 4 + wv;
  const float4 v = *(const float4*)(x + (size_t)row * DIM + lane * 4);
  sq[wv][lane * 4 + 0] = v.x * v.x;
  sq[wv][lane * 4 + 1] = v.y * v.y;
  sq[wv][lane * 4 + 2] = v.z * v.z;
  sq[wv][lane * 4 + 3] = v.w * v.w;
  __syncthreads();
  if (lane < 16) {
    const int j = lane & 7, hb = (lane >> 3) * 128;
    float r = sq[wv][hb + j];
    for (int i = 1; i < 16; ++i) r += sq[wv][hb + i * 8 + j];  // sequential, ascending
    rb[wv][lane] = r;
  }
  __syncthreads();
  if (lane == 0) {
    const float* r = rb[wv];
    const float h0 = ((r[0] + r[1]) + (r[2] + r[3])) + ((r[4] + r[5]) + (r[6] + r[7]));
    const float h1 = ((r[8] + r[9]) + (r[10] + r[11])) + ((r[12] + r[13]) + (r[14] + r[15]));
    out[row] = h0 + h1;
  }
}

// ---------------- prep: f16 hi+lo images (x8192) + hv + zero counters ----------------
__global__ __launch_bounds__(256) void vq_prep(const float* __restrict__ w,
                                               u16* __restrict__ imgh,
                                               u16* __restrict__ imgl,
                                               float* __restrict__ hv,
                                               int* __restrict__ cnt) {
  if (blockIdx.x == 0 && threadIdx.x == 0) { cnt[0] = 0; cnt[1] = 0; }
  const int wv = threadIdx.x >> 6, lane = threadIdx.x & 63;
  const int code = blockIdx.x * 4 + wv;
  const float4 v = *(const float4*)(w + (size_t)code * DIM + lane * 4);
  float xs[4] = {v.x * 8192.0f, v.y * 8192.0f, v.z * 8192.0f, v.w * 8192.0f};
  ushort4 uh, ul;
  unsigned short* ph = (unsigned short*)&uh;
  unsigned short* pl = (unsigned short*)&ul;
#pragma unroll
  for (int k = 0; k < 4; ++k) {
    const _Float16 h = (_Float16)xs[k];
    ph[k] = __builtin_bit_cast(u16, h);
    pl[k] = __builtin_bit_cast(u16, (_Float16)(xs[k] - (float)h));
  }
  *(ushort4*)(imgh + (size_t)code * DIM + lane * 4) = uh;
  *(ushort4*)(imgl + (size_t)code * DIM + lane * 4) = ul;
  double s = 0.0;
  s = fma((double)v.x, (double)v.x, s);
  s = fma((double)v.y, (double)v.y, s);
  s = fma((double)v.z, (double)v.z, s);
  s = fma((double)v.w, (double)v.w, s);
#pragma unroll
  for (int m = 1; m <= 32; m <<= 1) s += __shfl_xor(s, m, 64);
  if (lane == 0) hv[code] = (float)(4096.0 * s);
}

// merge two ascending sorted 4-tuples -> smallest 4 of union
#define MERGE4(a1, a2, a3, a4, b1, b2, b3, b4)                          \
  {                                                                     \
    const unsigned x11 = max(a1, b1);                                   \
    const unsigned o1 = min(a1, b1);                                    \
    const unsigned o2 = min(min(a2, b2), x11);                          \
    const unsigned x21 = max(a2, b1), x12 = max(a1, b2);                \
    const unsigned o3 = min(min(a3, b3), min(x21, x12));                \
    const unsigned x31 = max(a3, b1), x22 = max(a2, b2), x13 = max(a1, b3); \
    const unsigned o4 = min(min(a4, b4), min(min(x31, x22), x13));      \
    a1 = o1; a2 = o2; a3 = o3; a4 = o4;                                 \
  }

// ---------------- main: LDS-staged f16 MFMA + per-row top-4 int keys + flag ----------------
// r12-verbatim structure (333us). grid 512 x 256; wave owns 32 rows, all 8192 codes.
__global__ __launch_bounds__(256, 3) void vq_main(const float* __restrict__ z,
                                                  const u16* __restrict__ img,
                                                  const float* __restrict__ hv,
                                                  int4* __restrict__ top3,
                                                  int* __restrict__ cnt,
                                                  int* __restrict__ list,
                                                  u64* __restrict__ mkey,
                                                  unsigned* __restrict__ vminG) {
  __shared__ __align__(16) char lds[2][16384];
  const int tid = threadIdx.x, wv = tid >> 6, lane = tid & 63;
  const int ll = lane & 15, lh = lane >> 4;
  const int myrow = blockIdx.x * 128 + wv * 32;

  f16x8 A[2][8];
#pragma unroll
  for (int rt = 0; rt < 2; ++rt) {
    const float* zr = z + (size_t)(myrow + rt * 16 + ll) * DIM;
#pragma unroll
    for (int c = 0; c < 8; ++c) {
      const float4 a = *(const float4*)(zr + c * 32 + lh * 8);
      const float4 b = *(const float4*)(zr + c * 32 + lh * 8 + 4);
      f16x8 t;
      t[0] = (_Float16)a.x; t[1] = (_Float16)a.y;
      t[2] = (_Float16)a.z; t[3] = (_Float16)a.w;
      t[4] = (_Float16)b.x; t[5] = (_Float16)b.y;
      t[6] = (_Float16)b.z; t[7] = (_Float16)b.w;
      A[rt][c] = t;
    }
  }

  unsigned k1[8], k2[8], k3[8], k4[8];
#pragma unroll
  for (int s = 0; s < 8; ++s) {
    k1[s] = 0xFFFFFFFFu; k2[s] = 0xFFFFFFFFu;
    k3[s] = 0xFFFFFFFFu; k4[s] = 0xFFFFFFFFu;
  }

  unsigned soff[4];
#pragma unroll
  for (int p = 0; p < 4; ++p)
    soff[p] = (unsigned)((lane & 31) * 512 + ((p * 4 + wv) * 2 + (lane >> 5)) * 16);

  auto STAGE = [&](int t, int buf) {
    const char* src = (const char*)img + (size_t)t * 16384;
#pragma unroll
    for (int p = 0; p < 4; ++p) {
      __builtin_amdgcn_global_load_lds(
          (const __attribute__((address_space(1))) unsigned int*)(src + soff[p]),
          (__attribute__((address_space(3))) unsigned int*)(&lds[buf][(p * 4 + wv) * 1024]),
          16, 0, 0);
    }
  };

  const int rbase = lh * 512 + ll * 16;

  STAGE(0, 0);
  __syncthreads();
#pragma unroll 1
  for (int t = 0; t < 256; ++t) {
    const int buf = t & 1;
    if (t + 1 < 256) STAGE(t + 1, buf ^ 1);

    const float hb0 = fmaf(hv[t * 32 + ll], 512.0f, 262144.0f);  // (hv+512)*512
    const float hb1 = fmaf(hv[t * 32 + 16 + ll], 512.0f, 262144.0f);
    const char* bp = &lds[buf][rbase];

    f4v a00 = (f4v){0.f, 0.f, 0.f, 0.f}, a01 = (f4v){0.f, 0.f, 0.f, 0.f};
    f4v a10 = (f4v){0.f, 0.f, 0.f, 0.f}, a11 = (f4v){0.f, 0.f, 0.f, 0.f};
#pragma unroll
    for (int c = 0; c < 8; ++c) {
      const f16x8 b0 = *(const f16x8*)(bp + c * 2048);
      const f16x8 b1 = *(const f16x8*)(bp + c * 2048 + 256);
      a00 = __builtin_amdgcn_mfma_f32_16x16x32_f16(A[0][c], b0, a00, 0, 0, 0);
      a01 = __builtin_amdgcn_mfma_f32_16x16x32_f16(A[0][c], b1, a01, 0, 0, 0);
      a10 = __builtin_amdgcn_mfma_f32_16x16x32_f16(A[1][c], b0, a10, 0, 0, 0);
      a11 = __builtin_amdgcn_mfma_f32_16x16x32_f16(A[1][c], b1, a11, 0, 0, 0);
    }

    const unsigned iv0 = (unsigned)(t * 32 + ll);
    const unsigned iv1 = iv0 + 16u;
#pragma unroll
    for (int rt = 0; rt < 2; ++rt) {
      const f4v& c0 = rt ? a10 : a00;
      const f4v& c1 = rt ? a11 : a01;
#pragma unroll
      for (int j = 0; j < 4; ++j) {
        const int s = rt * 4 + j;
        const float u0 = fmaf(c0[j], -512.0f, hb0);
        const unsigned key0 = (((unsigned)u0) << 13) | iv0;
        const unsigned n1 = min(k1[s], key0);
        const unsigned n2 = med3u(k1[s], key0, k2[s]);
        const unsigned n3 = med3u(k2[s], key0, k3[s]);
        const unsigned n4 = med3u(k3[s], key0, k4[s]);
        const float u1 = fmaf(c1[j], -512.0f, hb1);
        const unsigned key1 = (((unsigned)u1) << 13) | iv1;
        k1[s] = min(n1, key1);
        k2[s] = med3u(n1, key1, n2);
        k3[s] = med3u(n2, key1, n3);
        k4[s] = med3u(n3, key1, n4);
      }
    }
    __syncthreads();
  }

#pragma unroll
  for (int rt = 0; rt < 2; ++rt)
#pragma unroll
    for (int j = 0; j < 4; ++j) {
      const int s = rt * 4 + j;
      unsigned a1 = k1[s], a2 = k2[s], a3 = k3[s], a4 = k4[s];
#pragma unroll
      for (int m = 1; m <= 8; m <<= 1) {
        unsigned b1 = (unsigned)__shfl_xor((int)a1, m, 64);
        unsigned b2 = (unsigned)__shfl_xor((int)a2, m, 64);
        unsigned b3 = (unsigned)__shfl_xor((int)a3, m, 64);
        unsigned b4 = (unsigned)__shfl_xor((int)a4, m, 64);
        MERGE4(a1, a2, a3, a4, b1, b2, b3, b4);
      }
      if (ll == 0) {  // C/D: col=lane&15, row=(lane>>4)*4+j
        const int row = myrow + rt * 16 + lh * 4 + j;
        const int flag = ((a4 >> 13) - (a1 >> 13)) < TAU_INT ? 1 : 0;
        top3[row] = make_int4((int)(a1 & 0x1FFFu), (int)(a2 & 0x1FFFu), (int)(a3 & 0x1FFFu),
                              (int)(((a1 >> 13) << 1) | (unsigned)flag));
        if (flag) {
          mkey[row] = ~0ull;
          vminG[row] = 0xFFFFFFFFu;
          list[atomicAdd(cnt, 1)] = row;
        }
      }
    }
}

// ---------------- refine (unflagged): np-replica s over top-3, first-index tie ----------------
__global__ __launch_bounds__(256) void vq_refine(const float* __restrict__ z,
                                                 const float* __restrict__ w,
                                                 const float* __restrict__ A32,
                                                 const float* __restrict__ C32,
                                                 const int4* __restrict__ top3,
                                                 float* __restrict__ out,
                                                 double* __restrict__ drow) {
  const int wv = threadIdx.x >> 6, lane = threadIdx.x & 63;
  const int row = blockIdx.x * 4 + wv;
  const int4 cc = top3[row];
  if (cc.w & 1) return;  // flagged -> fb path owns this row
  const float4 zv = *(const float4*)(z + (size_t)row * DIM + lane * 4);
  const double z0 = (double)zv.x, z1 = (double)zv.y, z2 = (double)zv.z, z3 = (double)zv.w;
  const int cand[3] = {cc.x, cc.y, cc.z};
  float4 ev[3];
  float sc[3];
  const float A = A32[row];
#pragma unroll
  for (int k = 0; k < 3; ++k) {
    ev[k] = *(const float4*)(w + (size_t)cand[k] * DIM + lane * 4);
    double d = 0.0;
    d = fma(z0, (double)ev[k].x, d);
    d = fma(z1, (double)ev[k].y, d);
    d = fma(z2, (double)ev[k].z, d);
    d = fma(z3, (double)ev[k].w, d);
#pragma unroll
    for (int m = 1; m <= 32; m <<= 1) d += __shfl_xor(d, m, 64);
    sc[k] = np_score(A, (float)d, C32[cand[k]]);
  }
  int win = cand[0], wk = 0;
  float sw = sc[0];
#pragma unroll
  for (int k = 1; k < 3; ++k) {
    const bool take = (sc[k] < sw) || (sc[k] == sw && cand[k] < win);
    sw = take ? sc[k] : sw;
    win = take ? cand[k] : win;
    wk = take ? k : wk;
  }
  const float4 q = ev[wk];
  *(float4*)(out + (size_t)row * DIM + lane * 4) = q;
  double dd = 0.0, tt;
  tt = (double)zv.x - (double)q.x; dd = fma(tt, tt, dd);
  tt = (double)zv.y - (double)q.y; dd = fma(tt, tt, dd);
  tt = (double)zv.z - (double)q.z; dd = fma(tt, tt, dd);
  tt = (double)zv.w - (double)q.w; dd = fma(tt, tt, dd);
#pragma unroll
  for (int m = 1; m <= 32; m <<= 1) dd += __shfl_xor(dd, m, 64);
  if (lane == 0) {
    out[OUT_IDX + row] = (float)win;
    drow[row] = dd;
  }
}

// ---------------- fb (flagged rows): 3-term split-f16 MFMA, 2 cheap passes ----------------
// grid 1024 = 64 chunk-slots x 16 slices (16 tiles each). Block = 128 gathered rows
// x 512 codes. 12 INDEPENDENT accumulators (hh/lh/hl x 4 quadrants) -> issue-bound
// (r15's 3-deep same-acc chains stalled at ~30cyc MFMA latency, 1 wave/SIMD).
// PASS 0: per-row accurate min -> vminG. PASS 1: identical arithmetic, emit codes
// with v <= vmin + MARG (0.45 proven: np worst 0.38 + 2x split err 0.01).
template <int PASS>
__global__ __launch_bounds__(256, 2) void vq_fb(const float* __restrict__ z,
                                                const u16* __restrict__ imgh,
                                                const u16* __restrict__ imgl,
                                                const float* __restrict__ hv,
                                                const int* __restrict__ cnt,
                                                const int* __restrict__ list,
                                                unsigned* __restrict__ vminG,
                                                int* __restrict__ gcnt,
                                                int2* __restrict__ cands) {
  __shared__ __align__(16) char lds[2][32768];  // hi 16K | lo 16K per buffer
  const int tid = threadIdx.x, wv = tid >> 6, lane = tid & 63;
  const int ll = lane & 15, lh = lane >> 4;
  const int n = *cnt;
  const int slice = blockIdx.x & 15;  // 16 slices x 16 tiles
  unsigned soff[4];
#pragma unroll
  for (int p = 0; p < 4; ++p)
    soff[p] = (unsigned)((lane & 31) * 512 + ((p * 4 + wv) * 2 + (lane >> 5)) * 16);
  const int rbase = lh * 512 + ll * 16;

  auto STAGE = [&](int t, int buf) {
    const char* sh = (const char*)imgh + (size_t)t * 16384;
    const char* sl = (const char*)imgl + (size_t)t * 16384;
#pragma unroll
    for (int p = 0; p < 4; ++p) {
      __builtin_amdgcn_global_load_lds(
          (const __attribute__((address_space(1))) unsigned int*)(sh + soff[p]),
          (__attribute__((address_space(3))) unsigned int*)(&lds[buf][(p * 4 + wv) * 1024]),
          16, 0, 0);
      __builtin_amdgcn_global_load_lds(
          (const __attribute__((address_space(1))) unsigned int*)(sl + soff[p]),
          (__attribute__((address_space(3))) unsigned int*)(&lds[buf][16384 + (p * 4 + wv) * 1024]),
          16, 0, 0);
    }
  };

#pragma unroll 1
  for (int chunk = (int)(blockIdx.x >> 4); chunk * 128 < n; chunk += 64) {
    // gather A hi/lo for this wave's 32 rows
    f16x8 Ah[2][8], Al[2][8];
#pragma unroll
    for (int rt = 0; rt < 2; ++rt) {
      const int ri = min(chunk * 128 + wv * 32 + rt * 16 + ll, n - 1);
      const float* zr = z + (size_t)list[ri] * DIM;
#pragma unroll
      for (int c = 0; c < 8; ++c) {
        const float4 a = *(const float4*)(zr + c * 32 + lh * 8);
        const float4 b = *(const float4*)(zr + c * 32 + lh * 8 + 4);
        float xs[8] = {a.x, a.y, a.z, a.w, b.x, b.y, b.z, b.w};
        f16x8 th, tl;
#pragma unroll
        for (int k = 0; k < 8; ++k) {
          const _Float16 h = (_Float16)xs[k];
          th[k] = h;
          tl[k] = (_Float16)(xs[k] - (float)h);
        }
        Ah[rt][c] = th;
        Al[rt][c] = tl;
      }
    }
    float vmin[2][4], vlim[2][4];
    int rowv[2][4];
#pragma unroll
    for (int rt = 0; rt < 2; ++rt)
#pragma unroll
      for (int j = 0; j < 4; ++j) {
        const int ri = min(chunk * 128 + wv * 32 + rt * 16 + lh * 4 + j, n - 1);
        rowv[rt][j] = list[ri];
        vmin[rt][j] = 3.0e38f;
        if (PASS == 1) vlim[rt][j] = fmono_inv(vminG[rowv[rt][j]]) + MARG;
      }

    STAGE(slice * 16, 0);
    __syncthreads();
#pragma unroll 1
    for (int tt = 0; tt < 16; ++tt) {
      const int t = slice * 16 + tt, buf = tt & 1;
      if (tt + 1 < 16) STAGE(slice * 16 + tt + 1, buf ^ 1);
      const float hv0 = hv[t * 32 + ll], hv1 = hv[t * 32 + 16 + ll];
      const char* bp = &lds[buf][rbase];

      // 12 independent accumulator chains: hh/lh/hl x (rt, ct)
      f4v h00 = (f4v){0.f,0.f,0.f,0.f}, h01 = h00, h10 = h00, h11 = h00;
      f4v l00 = h00, l01 = h00, l10 = h00, l11 = h00;
      f4v m00 = h00, m01 = h00, m10 = h00, m11 = h00;
#pragma unroll
      for (int c = 0; c < 8; ++c) {
        const f16x8 bh0 = *(const f16x8*)(bp + c * 2048);
        const f16x8 bh1 = *(const f16x8*)(bp + c * 2048 + 256);
        const f16x8 bl0 = *(const f16x8*)(bp + 16384 + c * 2048);
        const f16x8 bl1 = *(const f16x8*)(bp + 16384 + c * 2048 + 256);
        h00 = __builtin_amdgcn_mfma_f32_16x16x32_f16(Ah[0][c], bh0, h00, 0, 0, 0);
        h01 = __builtin_amdgcn_mfma_f32_16x16x32_f16(Ah[0][c], bh1, h01, 0, 0, 0);
        h10 = __builtin_amdgcn_mfma_f32_16x16x32_f16(Ah[1][c], bh0, h10, 0, 0, 0);
        h11 = __builtin_amdgcn_mfma_f32_16x16x32_f16(Ah[1][c], bh1, h11, 0, 0, 0);
        l00 = __builtin_amdgcn_mfma_f32_16x16x32_f16(Al[0][c], bh0, l00, 0, 0, 0);
        l01 = __builtin_amdgcn_mfma_f32_16x16x32_f16(Al[0][c], bh1, l01, 0, 0, 0);
        l10 = __builtin_amdgcn_mfma_f32_16x16x32_f16(Al[1][c], bh0, l10, 0, 0, 0);
        l11 = __builtin_amdgcn_mfma_f32_16x16x32_f16(Al[1][c], bh1, l11, 0, 0, 0);
        m00 = __builtin_amdgcn_mfma_f32_16x16x32_f16(Ah[0][c], bl0, m00, 0, 0, 0);
        m01 = __builtin_amdgcn_mfma_f32_16x16x32_f16(Ah[0][c], bl1, m01, 0, 0, 0);
        m10 = __builtin_amdgcn_mfma_f32_16x16x32_f16(Ah[1][c], bl0, m10, 0, 0, 0);
        m11 = __builtin_amdgcn_mfma_f32_16x16x32_f16(Ah[1][c], bl1, m11, 0, 0, 0);
      }

#pragma unroll
      for (int rt = 0; rt < 2; ++rt) {
        const f4v& ch0 = rt ? h10 : h00;
        const f4v& cl0 = rt ? l10 : l00;
        const f4v& cm0 = rt ? m10 : m00;
        const f4v& ch1 = rt ? h11 : h01;
        const f4v& cl1 = rt ? l11 : l01;
        const f4v& cm1 = rt ? m11 : m01;
#pragma unroll
        for (int j = 0; j < 4; ++j) {
          const float v0 = hv0 - ((ch0[j] + cl0[j]) + cm0[j]);
          const float v1 = hv1 - ((ch1[j] + cl1[j]) + cm1[j]);
          if (PASS == 0) {
            vmin[rt][j] = fminf(vmin[rt][j], fminf(v0, v1));
          } else {
            if (v0 <= vlim[rt][j]) {
              const int slot = atomicAdd(gcnt, 1);
              if (slot < MAXC) cands[slot] = make_int2(rowv[rt][j], t * 32 + ll);
            }
            if (v1 <= vlim[rt][j]) {
              const int slot = atomicAdd(gcnt, 1);
              if (slot < MAXC) cands[slot] = make_int2(rowv[rt][j], t * 32 + 16 + ll);
            }
          }
        }
      }
      __syncthreads();
    }

    if (PASS == 0) {
#pragma unroll
      for (int rt = 0; rt < 2; ++rt)
#pragma unroll
        for (int j = 0; j < 4; ++j) {
          float vm = vmin[rt][j];
#pragma unroll
          for (int m = 1; m <= 8; m <<= 1) vm = fminf(vm, __shfl_xor(vm, m, 64));
          if (ll == 0) atomicMin(&vminG[rowv[rt][j]], fmono(vm));
        }
    }
    __syncthreads();
  }
}

// ---------------- exact: np-replica score per candidate -> atomicMin key ----------------
__global__ __launch_bounds__(256) void vq_exact(const float* __restrict__ z,
                                                const float* __restrict__ w,
                                                const float* __restrict__ A32,
                                                const float* __restrict__ C32,
                                                const int* __restrict__ gcnt,
                                                const int2* __restrict__ cands,
                                                u64* __restrict__ mkey) {
  const int wv = threadIdx.x >> 6, lane = threadIdx.x & 63;
  const int m = min(*gcnt, MAXC);
  for (int k = blockIdx.x * 4 + wv; k < m; k += 1024) {
    const int2 c = cands[k];
    const float4 zv = *(const float4*)(z + (size_t)c.x * DIM + lane * 4);
    const float4 ev = *(const float4*)(w + (size_t)c.y * DIM + lane * 4);
    double d = 0.0;
    d = fma((double)zv.x, (double)ev.x, d);
    d = fma((double)zv.y, (double)ev.y, d);
    d = fma((double)zv.z, (double)ev.z, d);
    d = fma((double)zv.w, (double)ev.w, d);
#pragma unroll
    for (int mm = 1; mm <= 32; mm <<= 1) d += __shfl_xor(d, mm, 64);
    const float s = np_score(A32[c.x], (float)d, C32[c.y]);
    if (lane == 0) atomicMin(&mkey[c.x], ((u64)fmono(s) << 13) | (u64)c.y);
  }
}

// ---------------- fallback write: winner -> z_q, idx, drow ----------------
__global__ __launch_bounds__(256) void vq_fb_write(const float* __restrict__ z,
                                                   const float* __restrict__ w,
                                                   const int* __restrict__ cnt,
                                                   const int* __restrict__ list,
                                                   const u64* __restrict__ mkey,
                                                   float* __restrict__ out,
                                                   double* __restrict__ drow) {
  const int wv = threadIdx.x >> 6, lane = threadIdx.x & 63;
  const int n = *cnt;
  for (int k = blockIdx.x * 4 + wv; k < n; k += 1024) {
    const int row = list[k];
    const int win = (int)(mkey[row] & 0x1FFFull);
    const float4 zv = *(const float4*)(z + (size_t)row * DIM + lane * 4);
    const float4 q = *(const float4*)(w + (size_t)win * DIM + lane * 4);
    *(float4*)(out + (size_t)row * DIM + lane * 4) = q;
    double dd = 0.0, tt;
    tt = (double)zv.x - (double)q.x; dd = fma(tt, tt, dd);
    tt = (double)zv.y - (double)q.y; dd = fma(tt, tt, dd);
    tt = (double)zv.z - (double)q.z; dd = fma(tt, tt, dd);
    tt = (double)zv.w - (double)q.w; dd = fma(tt, tt, dd);
#pragma unroll
    for (int m = 1; m <= 32; m <<= 1) dd += __shfl_xor(dd, m, 64);
    if (lane == 0) {
      out[OUT_IDX + row] = (float)win;
      drow[row] = dd;
    }
  }
}

// ---------------- loss: deterministic f64 reduction ----------------
__global__ __launch_bounds__(256) void vq_loss(const double* __restrict__ drow,
                                               float* __restrict__ out) {
  __shared__ double sd[256];
  double s = 0.0;
  for (int i = threadIdx.x; i < NROWS; i += 256) s += drow[i];
  sd[threadIdx.x] = s;
  __syncthreads();
  if (threadIdx.x == 0) {
    double tot = 0.0;
    for (int i = 0; i < 256; ++i) tot += sd[i];
    const float loss = (float)(tot / 16777216.0);
    out[OUT_L0] = loss;
    out[OUT_L1] = loss;
  }
}

extern "C" void kernel_launch(void* const* d_in, const int* in_sizes, int n_in,
                              void* d_out, int out_size, void* d_ws, size_t ws_size,
                              hipStream_t stream) {
  const float* z = (const float*)d_in[0];  // f32 [65536, 256]
  const float* w = (const float*)d_in[1];  // f32 [8192, 256]
  float* out = (float*)d_out;
  unsigned char* ws = (unsigned char*)d_ws;
  u16* imgh = (u16*)(ws + WS_IMG);
  u16* imgl = (u16*)(ws + WS_IMGL);
  float* hv = (float*)(ws + WS_HV);
  float* C32 = (float*)(ws + WS_C32);
  float* A32 = (float*)(ws + WS_A32);
  int4* top3 = (int4*)(ws + WS_TOP3);
  double* drow = (double*)(ws + WS_DROW);
  int* cnt = (int*)(ws + WS_CNT);  // [0]=flagged, [1]=cands
  int* list = (int*)(ws + WS_LIST);
  u64* mkey = (u64*)(ws + WS_MKEY);
  unsigned* vminG = (unsigned*)(ws + WS_VMIN);
  int2* cands = (int2*)(ws + WS_CAND);

  vq_prep<<<NCODES / 4, 256, 0, stream>>>(w, imgh, imgl, hv, cnt);
  vq_rowA<<<NCODES / 4, 256, 0, stream>>>(w, C32);
  vq_rowA<<<NROWS / 4, 256, 0, stream>>>(z, A32);
  vq_main<<<NROWS / 128, 256, 0, stream>>>(z, imgh, hv, top3, cnt, list, mkey, vminG);
  vq_refine<<<NROWS / 4, 256, 0, stream>>>(z, w, A32, C32, top3, out, drow);
  vq_fb<0><<<1024, 256, 0, stream>>>(z, imgh, imgl, hv, cnt, list, vminG, cnt + 1, cands);
  vq_fb<1><<<1024, 256, 0, stream>>>(z, imgh, imgl, hv, cnt, list, vminG, cnt + 1, cands);
  vq_exact<<<256, 256, 0, stream>>>(z, w, A32, C32, cnt + 1, cands, mkey);
  vq_fb_write<<<256, 256, 0, stream>>>(z, w, cnt, list, mkey, out, drow);
  vq_loss<<<1, 256, 0, stream>>>(drow, out);
}